// Round 6
// baseline (323.581 us; speedup 1.0000x reference)
//
#include <hip/hip_runtime.h>

#define HW_IMG (224*224)
#define SCALE 0.17677669529663687f   // 1/sqrt(32)

typedef short bf16x8 __attribute__((ext_vector_type(8)));
typedef float f32x4 __attribute__((ext_vector_type(4)));
union U4B8 { uint4 u; bf16x8 b; };

__device__ __forceinline__ unsigned bf16rn(float f) {
  unsigned u = __float_as_uint(f);
  return (u + 0x7fffu + ((u >> 16) & 1u)) >> 16;
}
__device__ __forceinline__ unsigned packbf(float a, float b) {
  return bf16rn(a) | (bf16rn(b) << 16);
}

// ---- prep1: qh[r] = in_b[r] + query.in_w[r,:]; cb[r] = out_b[r] + out_w[r,:].aob ----
__global__ void prep1_kernel(const float* __restrict__ query,
                             const float* __restrict__ in_w,
                             const float* __restrict__ in_b,
                             const float* __restrict__ out_w,
                             const float* __restrict__ aob,
                             const float* __restrict__ out_b,
                             float* __restrict__ qh,
                             float* __restrict__ cb) {
  const int r = blockIdx.x, tid = threadIdx.x;
  float p1 = query[tid] * in_w[r*256 + tid];
  float p2 = aob[tid]   * out_w[r*256 + tid];
  #pragma unroll
  for (int o = 32; o; o >>= 1) { p1 += __shfl_xor(p1, o); p2 += __shfl_xor(p2, o); }
  __shared__ float t1[4], t2[4];
  if ((tid & 63) == 0) { t1[tid>>6] = p1; t2[tid>>6] = p2; }
  __syncthreads();
  if (tid == 0) qh[r] = in_b[r] + t1[0]+t1[1]+t1[2]+t1[3];
  if (tid == 1) cb[r] = out_b[r] + t2[0]+t2[1]+t2[2]+t2[3];
}

// ---- prep2: qk bf16 B-fragments for mfma_f32_16x16x32_bf16 ----
__global__ void prep2_kernel(const float* __restrict__ qh,
                             const float* __restrict__ in_w,
                             unsigned short* __restrict__ qkf) {
  const int k = blockIdx.x;     // 0..7
  const int L = threadIdx.x;    // 0..63
  const int h = L & 15, q = L >> 4;
  unsigned short o[8];
  #pragma unroll
  for (int j = 0; j < 8; ++j) {
    float s = 0.f;
    if (h < 8) {
      const int c = k*32 + q*8 + j;
      #pragma unroll
      for (int dd = 0; dd < 32; ++dd)
        s += qh[h*32 + dd] * in_w[(256 + h*32 + dd)*256 + c];
      s *= SCALE;
    }
    o[j] = (unsigned short)bf16rn(s);
  }
  ushort4* dst = (ushort4*)(qkf + (size_t)(k*64 + L)*8);
  dst[0] = make_ushort4(o[0],o[1],o[2],o[3]);
  dst[1] = make_ushort4(o[4],o[5],o[6],o[7]);
}

// ---- prep3: wvT and (out_w @ attn_out_w)^T ----
__global__ void prep3_kernel(const float* __restrict__ in_w,
                             const float* __restrict__ aw,
                             const float* __restrict__ out_w,
                             float* __restrict__ wvT,
                             float* __restrict__ cwT) {
  const int o = blockIdx.x, t = threadIdx.x;
  wvT[t*256 + o] = in_w[(512 + o)*256 + t];
  float a = 0.f;
  #pragma unroll 4
  for (int k = 0; k < 256; ++k) a += out_w[o*256 + k] * aw[k*256 + t];
  cwT[t*256 + o] = a;
}

// ---- repack: X (B,C,H,W) fp32 -> Y[n][cg4][l196][c64] bf16, all streaming ----
// block = (image b, row-pair R 0..111, channel-group cg 0..3), 256 threads
__global__ __launch_bounds__(256) void repack_kernel(
    const float* __restrict__ X, unsigned short* __restrict__ Y) {
  __shared__ float T[64*68];                   // [ch][pos+pad]
  const int bx = blockIdx.x;
  const int g = (bx & 7)*448 + (bx >> 3);      // XCD swizzle (3584 = 8*448)
  const int cg = g & 3;
  const int rest = g >> 2;                     // 0..895
  const int R = rest % 112, b = rest / 112;
  const int pi = R / 7, rr = R % 7;
  const int tid = threadIdx.x;
  const float* xbase = X + ((size_t)b*256 + cg*64)*HW_IMG + (pi*14 + rr*2)*224;
  const int cq = tid & 15, posg = tid >> 4;
  const size_t nb = ((size_t)b*16 + pi)*16;    // patch base (+pj later)

  #pragma unroll 1
  for (int tt = 0; tt < 7; ++tt) {
    // load 64 ch x 64 pos (contiguous 256B runs per channel)
    #pragma unroll
    for (int k = 0; k < 4; ++k) {
      const int u = tid + 256*k;
      const int c = u >> 4, f = u & 15;
      const float4 v = *(const float4*)(xbase + (size_t)c*HW_IMG + tt*64 + f*4);
      *(float4*)&T[c*68 + f*4] = v;
    }
    __syncthreads();
    // store transposed: 4 pos x 4 ch per thread, 512B/wave coalesced
    #pragma unroll
    for (int k = 0; k < 4; ++k) {
      const int pl = posg + 16*k;
      const int p = tt*64 + pl;
      const int imgrow = p / 224, col = p - imgrow*224;
      const int pj = col / 14, jj = col - pj*14;
      const int l = rr*28 + imgrow*14 + jj;
      const float v0 = T[(4*cq+0)*68 + pl];
      const float v1 = T[(4*cq+1)*68 + pl];
      const float v2 = T[(4*cq+2)*68 + pl];
      const float v3 = T[(4*cq+3)*68 + pl];
      uint2 w; w.x = packbf(v0, v1); w.y = packbf(v2, v3);
      *(uint2*)(Y + ((((nb + pj)*4 + cg)*196 + l)*64 + cq*4)) = w;
    }
    __syncthreads();
  }
}

// ---- out transpose: pout[b][pos][c] -> out[b][c][pos] ----
__global__ void transpose_out(const float* __restrict__ pout, float* __restrict__ out) {
  __shared__ float T[64*65];
  const int b  = blockIdx.x;
  const int pc = blockIdx.y;
  const int cc = blockIdx.z;
  const int tid = threadIdx.x;
  const int lc = tid & 63, lr = tid >> 6;
  #pragma unroll
  for (int i = 0; i < 16; ++i) {
    const int p = i*4 + lr;
    T[p*65 + lc] = pout[((size_t)b*256 + pc*64 + p)*256 + cc*64 + lc];
  }
  __syncthreads();
  #pragma unroll
  for (int i = 0; i < 16; ++i) {
    const int c = i*4 + lr;
    out[((size_t)b*256 + cc*64 + c)*256 + pc*64 + lc] = T[lc*65 + c];
  }
}

// ---- main: one block per patch; tile from tidy Y; MFMA scores; VALU pooling ----
__global__ __launch_bounds__(256)
__attribute__((amdgpu_waves_per_eu(2, 8)))
void attnpool_main(
    const unsigned short* __restrict__ Y,
    const float* __restrict__ in_b,
    const unsigned short* __restrict__ qkf,
    const float* __restrict__ wvT,
    const float* __restrict__ cwT,
    const float* __restrict__ cb,
    float* __restrict__ pout,
    float* __restrict__ out) {
  // bf16 tile: element (r, c) -> u32 word r*160 + (c>>1) + 4*((r>>1)&7), lo = even c
  __shared__ float Xs[32*160];        // rows 28..31 zero pad
  __shared__ uint4 QKs[8][64];        // qk B-fragments [kstep][lane]
  __shared__ float Wl[32*8];          // tile alphas [l][h]
  __shared__ float Ms[32], Ss[32];    // per-wave max/sum staging [wid][hcol]
  __shared__ float SCs[8], Ds[8];

  const int tid = threadIdx.x;
  const int wid = tid >> 6;
  const int lane = tid & 63;
  const int bid = blockIdx.x;
  const int n = (bid & 7) * 256 + (bid >> 3);   // XCD swizzle (2048%8==0)
  const int b = n >> 8, rem = n & 255, pi = rem >> 4, pj = rem & 15;

  for (int z = tid; z < 640; z += 256) Xs[28*160 + z] = 0.f;  // zero pad rows
  {  // stage qk fragments into LDS
    const uint4* qp = (const uint4*)qkf;
    ((uint4*)QKs)[tid]       = qp[tid];
    ((uint4*)QKs)[256 + tid] = qp[256 + tid];
  }

  // ---- loader: 896 uint4 per tile from Y (contiguous), 3.5/thread ----
  const unsigned short* Yn = Y + (size_t)n * (4*196*64);
  int soff[4], dstw[4];
  #pragma unroll
  for (int k = 0; k < 4; ++k) {
    const int u = tid + 256*k;
    const int uu = (u < 896) ? u : 0;
    const int cgk = uu / 224, rm = uu - cgk*224;
    const int lo = rm >> 3, c8 = rm & 7;
    soff[k] = (cgk*196 + lo)*64 + c8*8;          // halves, advance +1792/tile
    dstw[k] = lo*160 + cgk*32 + c8*4 + 4*((lo>>1)&7);
  }
  uint4 pf[4];
  auto fetchT = [&](int t) {
    const unsigned short* yt = Yn + t*1792;
    pf[0] = *(const uint4*)(yt + soff[0]);
    pf[1] = *(const uint4*)(yt + soff[1]);
    pf[2] = *(const uint4*)(yt + soff[2]);
    if (tid < 128) pf[3] = *(const uint4*)(yt + soff[3]);
  };
  auto commitT = [&]() {
    *(uint4*)&((unsigned*)Xs)[dstw[0]] = pf[0];
    *(uint4*)&((unsigned*)Xs)[dstw[1]] = pf[1];
    *(uint4*)&((unsigned*)Xs)[dstw[2]] = pf[2];
    if (tid < 128) *(uint4*)&((unsigned*)Xs)[dstw[3]] = pf[3];
  };

  // score-phase addressing (waves 0,1): A-frag row = wid*16 + (lane&15)
  const int arow = wid*16 + (lane & 15);
  const int abase = arow*640 + (lane>>4)*16 + ((arow>>1)&7)*16;
  const int hcol = lane & 15;
  const int rbase = wid*16 + (lane>>4)*4;

  // pool-phase addressing
  const int o = lane & 31, half = lane >> 5;
  const int pbase = o*16 + half*640;

  float m = -INFINITY, d = 0.f;
  float a0[8] = {0,0,0,0,0,0,0,0}, a1[8] = {0,0,0,0,0,0,0,0};

  fetchT(0);
  #pragma unroll 1
  for (int t = 0; t < 7; ++t) {
    __syncthreads();                       // pool(t-1) finished reading Xs
    commitT();
    __syncthreads();                       // Xs(t) [and QKs on t=0] visible
    if (t < 6) fetchT(t+1);

    float s0 = 0.f, s1 = 0.f, s2 = 0.f, s3 = 0.f;
    if (wid < 2) {
      f32x4 sc = {0.f, 0.f, 0.f, 0.f};
      #pragma unroll
      for (int k = 0; k < 8; ++k) {
        U4B8 a;  a.u  = *(const uint4*)((const char*)Xs + abase + k*64);
        U4B8 bq; bq.u = QKs[k][lane];
        sc = __builtin_amdgcn_mfma_f32_16x16x32_bf16(a.b, bq.b, sc, 0, 0, 0);
      }
      const bool pad = (wid == 1) && ((lane>>4) == 3);   // rows 28..31
      s0 = pad ? -INFINITY : sc[0];
      s1 = pad ? -INFINITY : sc[1];
      s2 = pad ? -INFINITY : sc[2];
      s3 = pad ? -INFINITY : sc[3];
      float mx = fmaxf(fmaxf(s0, s1), fmaxf(s2, s3));
      mx = fmaxf(mx, __shfl_xor(mx, 16));
      mx = fmaxf(mx, __shfl_xor(mx, 32));
      if (lane < 16) Ms[wid*16 + lane] = mx;
    }
    __syncthreads();                       // Ms ready
    if (wid < 2) {
      const float tm = fmaxf(Ms[hcol], Ms[16 + hcol]);
      const float mn = fmaxf(m, tm);
      const float scl = __expf(m - mn);
      m = mn;
      s0 = __expf(s0 - mn); s1 = __expf(s1 - mn);
      s2 = __expf(s2 - mn); s3 = __expf(s3 - mn);
      float ts = s0 + s1 + s2 + s3;
      ts += __shfl_xor(ts, 16); ts += __shfl_xor(ts, 32);
      if (lane < 16) Ss[wid*16 + lane] = ts;
      if (wid == 0 && lane < 8) SCs[lane] = scl;
      if (hcol < 8 && rbase < 28) {
        Wl[(rbase+0)*8 + hcol] = s0;
        Wl[(rbase+1)*8 + hcol] = s1;
        Wl[(rbase+2)*8 + hcol] = s2;
        Wl[(rbase+3)*8 + hcol] = s3;
      }
      d *= scl;
    }
    __syncthreads();                       // Wl/SCs ready
    if (wid < 2) d += Ss[hcol] + Ss[16 + hcol];
    // ---- pooling: heads (2*wid, 2*wid+1), c = 8o..8o+7, rows 2i+half ----
    {
      const float sa = SCs[2*wid], sb = SCs[2*wid + 1];
      #pragma unroll
      for (int nn = 0; nn < 8; ++nn) { a0[nn] *= sa; a1[nn] *= sb; }
      #pragma unroll
      for (int i = 0; i < 14; ++i) {
        const int r = 2*i + half;
        const uint4 xv = *(const uint4*)((const char*)Xs + pbase + i*1280 + (i&7)*16);
        const float2 w2 = *(const float2*)&Wl[r*8 + 2*wid];
        #pragma unroll
        for (int nn = 0; nn < 4; ++nn) {
          const unsigned uu = ((const unsigned*)&xv)[nn];
          const float xl = __uint_as_float(uu << 16);
          const float xh = __uint_as_float(uu & 0xffff0000u);
          a0[2*nn]   += w2.x * xl; a0[2*nn+1] += w2.x * xh;
          a1[2*nn]   += w2.y * xl; a1[2*nn+1] += w2.y * xh;
        }
      }
    }
  }

  if (wid == 0 && lane < 8) Ds[lane] = d;
  __syncthreads();
  {
    #pragma unroll
    for (int nn = 0; nn < 8; ++nn) {
      a0[nn] += __shfl_xor(a0[nn], 32);
      a1[nn] += __shfl_xor(a1[nn], 32);
    }
    if (half == 0) {
      const float i0 = 1.f / Ds[2*wid], i1 = 1.f / Ds[2*wid + 1];
      #pragma unroll
      for (int nn = 0; nn < 8; ++nn) { a0[nn] *= i0; a1[nn] *= i1; }
      f32x4 t0 = {a0[0], a0[1], a0[2], a0[3]};
      f32x4 t1 = {a0[4], a0[5], a0[6], a0[7]};
      f32x4 t2 = {a1[0], a1[1], a1[2], a1[3]};
      f32x4 t3 = {a1[4], a1[5], a1[6], a1[7]};
      *(f32x4*)&Xs[(2*wid)*256 + 8*o]       = t0;
      *(f32x4*)&Xs[(2*wid)*256 + 8*o + 4]   = t1;
      *(f32x4*)&Xs[(2*wid+1)*256 + 8*o]     = t2;
      *(f32x4*)&Xs[(2*wid+1)*256 + 8*o + 4] = t3;
    }
  }
  __syncthreads();
  {  // ctx[c'] = bv[c'] + sum_c wvT[c][c'] * pooled[h(c')][c]
    const int h2 = tid >> 5;
    float a = in_b[512 + tid];
    #pragma unroll 8
    for (int c = 0; c < 256; ++c) a += wvT[c*256 + tid] * Xs[h2*256 + c];
    Xs[2048 + tid] = a;
  }
  __syncthreads();
  {  // out[o'] = cb[o'] + sum_k cwT[k][o'] * ctx[k]
    float oo = cb[tid];
    #pragma unroll 8
    for (int k = 0; k < 256; ++k) oo += cwT[k*256 + tid] * Xs[2048 + k];
    if (pout) pout[(size_t)n*256 + tid] = oo;                   // coalesced
    else out[(((size_t)b*256 + tid)*16 + pi)*16 + pj] = oo;     // fallback
  }
}

extern "C" void kernel_launch(void* const* d_in, const int* in_sizes, int n_in,
                              void* d_out, int out_size, void* d_ws, size_t ws_size,
                              hipStream_t stream) {
  const float* X    = (const float*)d_in[0];
  const float* q    = (const float*)d_in[1];
  const float* in_w = (const float*)d_in[2];
  const float* in_b = (const float*)d_in[3];
  const float* aw   = (const float*)d_in[4];
  const float* aob  = (const float*)d_in[5];
  const float* ow   = (const float*)d_in[6];
  const float* ob   = (const float*)d_in[7];
  float* out = (float*)d_out;

  float* wsf = (float*)d_ws;
  float* qh   = wsf;                        // 256
  float* cb   = wsf + 256;                  // 256
  unsigned short* qkf = (unsigned short*)(wsf + 512);  // 8KB
  float* wvT  = wsf + 4096;                 // 65536
  float* cwT  = wsf + 4096 + 65536;         // 65536
  float* pout = wsf + 4096 + 2*65536;       // 524288 floats (2MB)
  unsigned short* Y = (unsigned short*)(wsf + 4096 + 2*65536 + 524288);  // 205.5MB

  hipLaunchKernelGGL(prep1_kernel, dim3(256),  dim3(256), 0, stream,
                     q, in_w, in_b, ow, aob, ob, qh, cb);
  hipLaunchKernelGGL(prep2_kernel, dim3(8),    dim3(64),  0, stream,
                     qh, in_w, qkf);
  hipLaunchKernelGGL(prep3_kernel, dim3(256),  dim3(256), 0, stream,
                     in_w, aw, ow, wvT, cwT);
  hipLaunchKernelGGL(repack_kernel, dim3(3584), dim3(256), 0, stream,
                     X, Y);
  hipLaunchKernelGGL(attnpool_main, dim3(2048), dim3(256), 0, stream,
                     Y, in_b, qkf, wvT, cwT, cb, pout, out);
  hipLaunchKernelGGL(transpose_out, dim3(8, 4, 4), dim3(256), 0, stream,
                     pout, out);
}